// Round 3
// baseline (14042.027 us; speedup 1.0000x reference)
//
#include <hip/hip_runtime.h>
#include <stdint.h>

#define B_   512
#define T_   512

typedef __attribute__((ext_vector_type(8))) __bf16 bf16x8;
typedef __attribute__((ext_vector_type(4))) float f32x4;
typedef __attribute__((ext_vector_type(8))) unsigned short u16x8;

// Layer geometry:
//   l : S   | C   | NPT | KT | XOFF | RS (LDS row stride, elems)
//   0 : 231 | 232 | 15  | 8  | 1    | 280
//   1 : 153 | 384 | 10  | 12 | 231  | 408
//   2 : 128 | 281 | 8   | 9  | 153  | 312
// Packed weights (bf16) in d_ws: per layer, 3 matrices (G1=W1*mask, G2=W2*mask, G3=Wa+Wb),
// chunk c = ((m*NPT + nt)*KT + kt)*64 + lane, 8 bf16:
//   elem i = G[nt*16 + (lane&15)][kt*32 + (lane>>4)*8 + i]  (zero outside S x C)
// Layer elem offsets: L0=0, L1=184320, L2=368640.

#define RS0 280
#define RS1 408
#define RS2 312

__device__ __forceinline__ uint16_t f2bf(float f){
  union { float f; uint32_t u; } v; v.f = f;
  uint32_t u = v.u;
  u += 0x7FFFu + ((u >> 16) & 1u);
  return (uint16_t)(u >> 16);
}
__device__ __forceinline__ float bf2f(uint16_t h){
  union { uint32_t u; float f; } v; v.u = ((uint32_t)h) << 16;
  return v.f;
}
__device__ __forceinline__ float sigm_f(float x){
  return __builtin_amdgcn_rcpf(1.0f + __builtin_amdgcn_exp2f(-1.4426950408889634f * x));
}
__device__ __forceinline__ float tanh_f(float x){
  return 2.0f * __builtin_amdgcn_rcpf(1.0f + __builtin_amdgcn_exp2f(-2.8853900817779268f * x)) - 1.0f;
}

__global__ void pack_w(const float* __restrict__ W1, const float* __restrict__ W2,
                       const float* __restrict__ Wa, const float* __restrict__ Wb,
                       const float* __restrict__ Msk, uint16_t* __restrict__ dst,
                       int NPT, int KT, int S, int C)
{
  int c = blockIdx.x * 256 + threadIdx.x;
  int chunks = 3 * NPT * KT * 64;
  if (c >= chunks) return;
  int perN = KT * 64;
  int n3 = c / perN, r = c % perN;
  int kt = r >> 6, lane = r & 63;
  int m = n3 / NPT, nt = n3 % NPT;
  int j = nt * 16 + (lane & 15);
  int kb = kt * 32 + (lane >> 4) * 8;
  u16x8 o;
  #pragma unroll
  for (int i = 0; i < 8; ++i){
    int k = kb + i;
    float v = 0.f;
    if (j < S && k < C){
      size_t idx = (size_t)j * C + k;
      if (m == 0)      v = W1[idx] * Msk[idx];
      else if (m == 1) v = W2[idx] * Msk[idx];
      else             v = Wa[idx] + Wb[idx];
    }
    o[i] = f2bf(v);
  }
  *(u16x8*)(dst + (size_t)c * 8) = o;
}

// ---- per-layer building blocks -------------------------------------------

template<int NPT, int KT>
__device__ __forceinline__ void load_tileset(const bf16x8* __restrict__ Wl8,
                                             int jt, int lane, bf16x8 (&w)[3][KT])
{
  const bf16x8* p = Wl8 + (size_t)((unsigned)jt * (unsigned)(KT * 64)) + lane;
  #pragma unroll
  for (int m = 0; m < 3; ++m){
    #pragma unroll
    for (int kt = 0; kt < KT; ++kt)
      w[m][kt] = p[(m * NPT * KT + kt) * 64];
  }
}

template<int LNUM, int S, int KT, int XOFF, int RSC, int RSN>
__device__ __forceinline__ void compute_tile(const bf16x8 (&a)[KT], const bf16x8 (&w)[3][KT],
    int jt, float B1, float B2, float B3,
    uint16_t* __restrict__ Xh, uint16_t* __restrict__ Xn, float* __restrict__ outp,
    int t, int b0, int llo, int lhi)
{
  f32x4 ac0 = {0.f,0.f,0.f,0.f}, ac1 = ac0, ac2 = ac0;
  #pragma unroll
  for (int kt = 0; kt < KT; ++kt){
    ac0 = __builtin_amdgcn_mfma_f32_16x16x32_bf16(a[kt], w[0][kt], ac0, 0, 0, 0);
    ac1 = __builtin_amdgcn_mfma_f32_16x16x32_bf16(a[kt], w[1][kt], ac1, 0, 0, 0);
    ac2 = __builtin_amdgcn_mfma_f32_16x16x32_bf16(a[kt], w[2][kt], ac2, 0, 0, 0);
  }
  const int j = jt * 16 + llo;
  const bool valid = (j < S);
  #pragma unroll
  for (int r = 0; r < 4; ++r){
    const int row = lhi * 4 + r;
    float ff1 = tanh_f(ac0[r] + B1);
    float ff2 = tanh_f(ac1[r] + B2);
    float tt  = sigm_f(ac2[r] + B3);
    float h = ff1 + tt * (ff2 - ff1);
    if (valid){
      uint16_t hb = f2bf(h);
      Xh[row * RSC + XOFF + j] = hb;
      if constexpr (LNUM < 2)
        Xn[row * RSN + j] = hb;
      else
        outp[((size_t)(b0 + row) * T_ + t) * 128 + j] = h;
    }
  }
}

__attribute__((amdgpu_waves_per_eu(2, 2)))
__global__ __launch_bounds__(512) void cfc_main(
    const float* __restrict__ elapsed, const float* __restrict__ enc,
    const float* __restrict__ b1_0, const float* __restrict__ b2_0,
    const float* __restrict__ ba0,  const float* __restrict__ bb0,
    const float* __restrict__ b1_1, const float* __restrict__ b2_1,
    const float* __restrict__ ba1,  const float* __restrict__ bb1,
    const float* __restrict__ b1_2, const float* __restrict__ b2_2,
    const float* __restrict__ ba2,  const float* __restrict__ bb2,
    const uint16_t* __restrict__ Wp, float* __restrict__ out)
{
  const int tid = threadIdx.x;
  const int wave = tid >> 6, lane = tid & 63;
  const int llo = lane & 15, lhi = lane >> 4;
  const int b0 = blockIdx.x * 16;

  __shared__ uint16_t X0[2 * 16 * RS0];
  __shared__ uint16_t X1[2 * 16 * RS1];
  __shared__ uint16_t X2[2 * 16 * RS2];

  for (int i = tid; i < 2 * 16 * RS0; i += 512) X0[i] = 0;
  for (int i = tid; i < 2 * 16 * RS1; i += 512) X1[i] = 0;
  for (int i = tid; i < 2 * 16 * RS2; i += 512) X2[i] = 0;
  __syncthreads();

  // initial hidden states
  for (int i = tid; i < 16 * 512; i += 512){
    int row = i >> 9, c = i & 511;
    float v = enc[(size_t)(b0 + row) * 512 + c];
    uint16_t hb = f2bf(v);
    if (c < 231)       X0[row * RS0 + 1 + c] = hb;
    else if (c < 384)  X1[row * RS1 + c] = hb;
    else               X2[row * RS2 + (c - 231)] = hb;
  }

  // biases -> registers. For L0 tile ji=1 use CLAMPED jt so wave 7's duplicate
  // of tile 14 computes bit-identical h (benign duplicate LDS write).
  float bias0[6], bias1[6], bias2[3];
  {
    const int j0 = wave * 16 + llo;                   // ji=0, jt=wave (<15)
    bias0[0] = b1_0[j0 < 231 ? j0 : 0]; bias0[0] = (j0 < 231) ? bias0[0] : 0.f;
    bias0[1] = (j0 < 231) ? b2_0[j0] : 0.f;
    bias0[2] = (j0 < 231) ? (ba0[j0] + bb0[j0]) : 0.f;
    const int jc = (wave + 8 < 15) ? (wave + 8) : 14; // clamped second tile
    const int j1 = jc * 16 + llo;
    bias0[3] = (j1 < 231) ? b1_0[j1] : 0.f;
    bias0[4] = (j1 < 231) ? b2_0[j1] : 0.f;
    bias0[5] = (j1 < 231) ? (ba0[j1] + bb0[j1]) : 0.f;
  }
  #pragma unroll
  for (int ji = 0; ji < 2; ++ji){
    const int jt = wave + ji * 8;
    const int j = jt * 16 + llo;
    const bool v1 = (jt < 10) && (j < 153);
    bias1[ji * 3 + 0] = v1 ? b1_1[j] : 0.f;
    bias1[ji * 3 + 1] = v1 ? b2_1[j] : 0.f;
    bias1[ji * 3 + 2] = v1 ? (ba1[j] + bb1[j]) : 0.f;
  }
  {
    const int j = wave * 16 + llo;
    const bool v2 = (j < 128);
    bias2[0] = v2 ? b1_2[j] : 0.f;
    bias2[1] = v2 ? b2_2[j] : 0.f;
    bias2[2] = v2 ? (ba2[j] + bb2[j]) : 0.f;
  }

  const bf16x8* W0_8 = (const bf16x8*)(Wp);
  const bf16x8* W1_8 = (const bf16x8*)(Wp + 184320);
  const bf16x8* W2_8 = (const bf16x8*)(Wp + 368640);
  const int jt0c = (wave + 8 < 15) ? (wave + 8) : 14;   // L0 clamped 2nd tile

  // x_0 into X0[buf 0], prefetch x_1
  float xt = 0.f;
  if (tid < 16){
    X0[tid * RS0] = f2bf(elapsed[(size_t)(b0 + tid) * T_]);
    xt = elapsed[(size_t)(b0 + tid) * T_ + 1];
  }
  __syncthreads();

  int cur = 0;
  #pragma unroll 1
  for (int t = 0; t < T_; ++t){
    const int nxt = cur ^ 1;
    uint16_t* X0c = X0 + cur * 16 * RS0; uint16_t* X0n = X0 + nxt * 16 * RS0;
    uint16_t* X1c = X1 + cur * 16 * RS1; uint16_t* X1n = X1 + nxt * 16 * RS1;
    uint16_t* X2c = X2 + cur * 16 * RS2; uint16_t* X2n = X2 + nxt * 16 * RS2;

    // ---------------- layer 0 : 15 tiles, KT=8 ----------------
    {
      bf16x8 a[8];
      const uint16_t* arow = X0c + llo * RS0 + lhi * 8;
      #pragma unroll
      for (int kt = 0; kt < 8; ++kt) a[kt] = *(const bf16x8*)(arow + kt * 32);

      bf16x8 wA[3][8], wB[3][8];
      load_tileset<15, 8>(W0_8, wave, lane, wA);
      load_tileset<15, 8>(W0_8, jt0c, lane, wB);       // branchless 2nd tile
      compute_tile<0, 231, 8, 1, RS0, RS1>(a, wA, wave, bias0[0], bias0[1], bias0[2],
                                           X0n, X1c, out, t, b0, llo, lhi);
      compute_tile<0, 231, 8, 1, RS0, RS1>(a, wB, jt0c, bias0[3], bias0[4], bias0[5],
                                           X0n, X1c, out, t, b0, llo, lhi);
    }
    __syncthreads();

    // ---------------- layer 1 : 10 tiles, KT=12 ----------------
    {
      bf16x8 a[12];
      const uint16_t* arow = X1c + llo * RS1 + lhi * 8;
      #pragma unroll
      for (int kt = 0; kt < 12; ++kt) a[kt] = *(const bf16x8*)(arow + kt * 32);

      bf16x8 wA[3][12];
      load_tileset<10, 12>(W1_8, wave, lane, wA);
      if (wave < 2){
        bf16x8 wB[3][12];
        load_tileset<10, 12>(W1_8, wave + 8, lane, wB);
        compute_tile<1, 153, 12, 231, RS1, RS2>(a, wA, wave, bias1[0], bias1[1], bias1[2],
                                                X1n, X2c, out, t, b0, llo, lhi);
        compute_tile<1, 153, 12, 231, RS1, RS2>(a, wB, wave + 8, bias1[3], bias1[4], bias1[5],
                                                X1n, X2c, out, t, b0, llo, lhi);
      } else {
        compute_tile<1, 153, 12, 231, RS1, RS2>(a, wA, wave, bias1[0], bias1[1], bias1[2],
                                                X1n, X2c, out, t, b0, llo, lhi);
      }
    }
    __syncthreads();

    // ---------------- layer 2 : 8 tiles, KT=9 ----------------
    {
      bf16x8 a[9];
      const uint16_t* arow = X2c + llo * RS2 + lhi * 8;
      #pragma unroll
      for (int kt = 0; kt < 9; ++kt) a[kt] = *(const bf16x8*)(arow + kt * 32);

      bf16x8 wA[3][9];
      load_tileset<8, 9>(W2_8, wave, lane, wA);
      compute_tile<2, 128, 9, 153, RS2, RS2>(a, wA, wave, bias2[0], bias2[1], bias2[2],
                                             X2n, nullptr, out, t, b0, llo, lhi);
    }

    // x_{t+1} into next buffer's input column
    if (tid < 16 && t + 1 < T_){
      X0n[tid * RS0] = f2bf(xt);
      if (t + 2 < T_) xt = elapsed[(size_t)(b0 + tid) * T_ + t + 2];
    }
    __syncthreads();
    cur = nxt;
  }

  // rnn_hidden = concat(h0,h1,h2); after 512 steps cur==0
  const size_t OH = (size_t)B_ * T_ * 128;
  for (int i = tid; i < 16 * 512; i += 512){
    int row = i >> 9, c = i & 511;
    float v;
    if (c < 231)      v = bf2f(X0[row * RS0 + 1 + c]);
    else if (c < 384) v = bf2f(X1[row * RS1 + c]);
    else              v = bf2f(X2[row * RS2 + (c - 231)]);
    out[OH + (size_t)(b0 + row) * 512 + c] = v;
  }
}

extern "C" void kernel_launch(void* const* d_in, const int* in_sizes, int n_in,
                              void* d_out, int out_size, void* d_ws, size_t ws_size,
                              hipStream_t stream)
{
  const float* elapsed = (const float*)d_in[0];
  const float* enc     = (const float*)d_in[1];
  const float* W1_0 = (const float*)d_in[2];  const float* b1_0 = (const float*)d_in[3];
  const float* W2_0 = (const float*)d_in[4];  const float* b2_0 = (const float*)d_in[5];
  const float* Wa0  = (const float*)d_in[6];  const float* ba0  = (const float*)d_in[7];
  const float* Wb0  = (const float*)d_in[8];  const float* bb0  = (const float*)d_in[9];
  const float* M0   = (const float*)d_in[10];
  const float* W1_1 = (const float*)d_in[11]; const float* b1_1 = (const float*)d_in[12];
  const float* W2_1 = (const float*)d_in[13]; const float* b2_1 = (const float*)d_in[14];
  const float* Wa1  = (const float*)d_in[15]; const float* ba1  = (const float*)d_in[16];
  const float* Wb1  = (const float*)d_in[17]; const float* bb1  = (const float*)d_in[18];
  const float* M1   = (const float*)d_in[19];
  const float* W1_2 = (const float*)d_in[20]; const float* b1_2 = (const float*)d_in[21];
  const float* W2_2 = (const float*)d_in[22]; const float* b2_2 = (const float*)d_in[23];
  const float* Wa2  = (const float*)d_in[24]; const float* ba2  = (const float*)d_in[25];
  const float* Wb2  = (const float*)d_in[26]; const float* bb2  = (const float*)d_in[27];
  const float* M2   = (const float*)d_in[28];

  uint16_t* wp = (uint16_t*)d_ws;

  pack_w<<<90, 256, 0, stream>>>(W1_0, W2_0, Wa0, Wb0, M0, wp,          15,  8, 231, 232);
  pack_w<<<90, 256, 0, stream>>>(W1_1, W2_1, Wa1, Wb1, M1, wp + 184320, 10, 12, 153, 384);
  pack_w<<<54, 256, 0, stream>>>(W1_2, W2_2, Wa2, Wb2, M2, wp + 368640,  8,  9, 128, 281);

  cfc_main<<<32, 512, 0, stream>>>(elapsed, enc,
                                   b1_0, b2_0, ba0, bb0,
                                   b1_1, b2_1, ba1, bb1,
                                   b1_2, b2_2, ba2, bb2,
                                   wp, (float*)d_out);
}

// Round 4
// 11462.567 us; speedup vs baseline: 1.2250x; 1.2250x over previous
//
#include <hip/hip_runtime.h>
#include <stdint.h>

#define B_   512
#define T_   512

typedef __attribute__((ext_vector_type(8))) __bf16 bf16x8;
typedef __attribute__((ext_vector_type(4))) float f32x4;
typedef __attribute__((ext_vector_type(8))) unsigned short u16x8;

// Layer geometry:
//   l : S   | C   | NPT | KT | XOFF | RS (LDS row stride, elems)
//   0 : 231 | 232 | 15  | 8  | 1    | 280
//   1 : 153 | 384 | 10  | 12 | 231  | 408
//   2 : 128 | 281 | 8   | 9  | 153  | 312
// Packed weights (bf16) in d_ws: per layer, 3 matrices (G1=W1*mask, G2=W2*mask, G3=Wa+Wb),
// chunk c = ((m*NPT + nt)*KT + kt)*64 + lane, 8 bf16:
//   elem i = G[nt*16 + (lane&15)][kt*32 + (lane>>4)*8 + i]  (zero outside S x C)
// Layer elem offsets: L0=0, L1=184320, L2=368640.

#define RS0 280
#define RS1 408
#define RS2 312

__device__ __forceinline__ uint16_t bfbits(float f){
  __bf16 h = (__bf16)f;                       // native RTNE cvt
  return __builtin_bit_cast(uint16_t, h);
}
__device__ __forceinline__ float bf2f(uint16_t h){
  union { uint32_t u; float f; } v; v.u = ((uint32_t)h) << 16;
  return v.f;
}
__device__ __forceinline__ float sigm_f(float x){
  return __builtin_amdgcn_rcpf(1.0f + __builtin_amdgcn_exp2f(-1.4426950408889634f * x));
}
__device__ __forceinline__ float tanh_f(float x){
  return 2.0f * __builtin_amdgcn_rcpf(1.0f + __builtin_amdgcn_exp2f(-2.8853900817779268f * x)) - 1.0f;
}

// lgkm-only barrier: LDS ops drained, global (weight) loads stay in flight.
#define BAR() do { asm volatile("s_waitcnt lgkmcnt(0)" ::: "memory"); \
                   __builtin_amdgcn_s_barrier(); } while(0)

__global__ void pack_w(const float* __restrict__ W1, const float* __restrict__ W2,
                       const float* __restrict__ Wa, const float* __restrict__ Wb,
                       const float* __restrict__ Msk, uint16_t* __restrict__ dst,
                       int NPT, int KT, int S, int C)
{
  int c = blockIdx.x * 256 + threadIdx.x;
  int chunks = 3 * NPT * KT * 64;
  if (c >= chunks) return;
  int perN = KT * 64;
  int n3 = c / perN, r = c % perN;
  int kt = r >> 6, lane = r & 63;
  int m = n3 / NPT, nt = n3 % NPT;
  int j = nt * 16 + (lane & 15);
  int kb = kt * 32 + (lane >> 4) * 8;
  u16x8 o;
  #pragma unroll
  for (int i = 0; i < 8; ++i){
    int k = kb + i;
    float v = 0.f;
    if (j < S && k < C){
      size_t idx = (size_t)j * C + k;
      if (m == 0)      v = W1[idx] * Msk[idx];
      else if (m == 1) v = W2[idx] * Msk[idx];
      else             v = Wa[idx] + Wb[idx];
    }
    o[i] = bfbits(v);
  }
  *(u16x8*)(dst + (size_t)c * 8) = o;
}

// ---- rolling-pipeline building blocks ------------------------------------

template<int KT> struct WG { bf16x8 v[KT]; };

template<int KT>
__device__ __forceinline__ void wload(const bf16x8* __restrict__ p, WG<KT>& g){
  #pragma unroll
  for (int k = 0; k < KT; ++k) g.v[k] = p[k * 64];
}

template<int KT>
__device__ __forceinline__ void wmfma(const bf16x8* a, const WG<KT>& g, f32x4& ac){
  #pragma unroll
  for (int k = 0; k < KT; ++k)
    ac = __builtin_amdgcn_mfma_f32_16x16x32_bf16(a[k], g.v[k], ac, 0, 0, 0);
}

template<int LNUM, int S, int XOFF, int RSC, int RSN>
__device__ __forceinline__ void epilogue(
    const f32x4& ac0, const f32x4& ac1, const f32x4& ac2, int jt,
    float B1, float B2, float B3,
    uint16_t* __restrict__ Xh, uint16_t* __restrict__ Xn,
    float* __restrict__ outp, int t, int b0, int llo, int lhi)
{
  const int j = jt * 16 + llo;
  const bool valid = (j < S);
  #pragma unroll
  for (int r = 0; r < 4; ++r){
    const int row = lhi * 4 + r;
    float ff1 = tanh_f(ac0[r] + B1);
    float ff2 = tanh_f(ac1[r] + B2);
    float tt  = sigm_f(ac2[r] + B3);
    float h = ff1 + tt * (ff2 - ff1);
    if (valid){
      uint16_t hb = bfbits(h);
      Xh[row * RSC + XOFF + j] = hb;
      if constexpr (LNUM < 2)
        Xn[row * RSN + j] = hb;
      else
        outp[((size_t)(b0 + row) * T_ + t) * 128 + j] = h;
    }
  }
}

__global__ __launch_bounds__(512, 2) void cfc_main(
    const float* __restrict__ elapsed, const float* __restrict__ enc,
    const float* __restrict__ b1_0, const float* __restrict__ b2_0,
    const float* __restrict__ ba0,  const float* __restrict__ bb0,
    const float* __restrict__ b1_1, const float* __restrict__ b2_1,
    const float* __restrict__ ba1,  const float* __restrict__ bb1,
    const float* __restrict__ b1_2, const float* __restrict__ b2_2,
    const float* __restrict__ ba2,  const float* __restrict__ bb2,
    const uint16_t* __restrict__ Wp, float* __restrict__ out)
{
  const int tid = threadIdx.x;
  const int wave = tid >> 6, lane = tid & 63;
  const int llo = lane & 15, lhi = lane >> 4;
  const int b0 = blockIdx.x * 16;

  // 96,768 B total LDS -> 1 block/CU -> 2 waves/SIMD -> 256-VGPR budget.
  __shared__ uint16_t X0[2 * 16 * RS0];
  __shared__ uint16_t X1[2 * 16 * RS1];
  __shared__ uint16_t X2[2 * 16 * RS2];
  __shared__ float    xl[T_ * 16];          // elapsed, transposed [t][row]

  for (int i = tid; i < 2 * 16 * RS0; i += 512) X0[i] = 0;
  for (int i = tid; i < 2 * 16 * RS1; i += 512) X1[i] = 0;
  for (int i = tid; i < 2 * 16 * RS2; i += 512) X2[i] = 0;
  // elapsed slice: read coalesced [row][t], scatter to [t][row]
  for (int i = tid; i < 16 * T_; i += 512){
    int row = i >> 9, t = i & 511;
    xl[t * 16 + row] = elapsed[(size_t)(b0 + row) * T_ + t];
  }
  __syncthreads();

  // initial hidden states
  for (int i = tid; i < 16 * 512; i += 512){
    int row = i >> 9, c = i & 511;
    float v = enc[(size_t)(b0 + row) * 512 + c];
    uint16_t hb = bfbits(v);
    if (c < 231)       X0[row * RS0 + 1 + c] = hb;
    else if (c < 384)  X1[row * RS1 + c] = hb;
    else               X2[row * RS2 + (c - 231)] = hb;
  }

  // tile assignment (per wave)
  const int jt0a = wave;                                  // L0 tile 1 (0..7)
  const int jt0b = (wave + 8 < 15) ? (wave + 8) : 14;     // L0 tile 2 (8..14; w7 dups 14)
  const int jt1a = wave;                                  // L1 tile 1 (0..7)
  const int jt1b = wave + 8;                              // L1 tile 2 (waves 0,1 only)
  const int jt2  = wave;                                  // L2 tile (0..7)

  // biases -> registers
  float b0A[3], b0B[3], b1A[3], b1B[3], b2r[3];
  {
    const int j = jt0a * 16 + llo; const bool v = (j < 231);
    b0A[0] = v ? b1_0[j] : 0.f; b0A[1] = v ? b2_0[j] : 0.f; b0A[2] = v ? (ba0[j] + bb0[j]) : 0.f;
  }
  {
    const int j = jt0b * 16 + llo; const bool v = (j < 231);
    b0B[0] = v ? b1_0[j] : 0.f; b0B[1] = v ? b2_0[j] : 0.f; b0B[2] = v ? (ba0[j] + bb0[j]) : 0.f;
  }
  {
    const int j = jt1a * 16 + llo; const bool v = (j < 153);
    b1A[0] = v ? b1_1[j] : 0.f; b1A[1] = v ? b2_1[j] : 0.f; b1A[2] = v ? (ba1[j] + bb1[j]) : 0.f;
  }
  {
    const int j = jt1b * 16 + llo; const bool v = (jt1b < 10) && (j < 153);
    b1B[0] = v ? b1_1[j] : 0.f; b1B[1] = v ? b2_1[j] : 0.f; b1B[2] = v ? (ba1[j] + bb1[j]) : 0.f;
  }
  {
    const int j = jt2 * 16 + llo; const bool v = (j < 128);
    b2r[0] = v ? b1_2[j] : 0.f; b2r[1] = v ? b2_2[j] : 0.f; b2r[2] = v ? (ba2[j] + bb2[j]) : 0.f;
  }

  // weight base pointers (per wave, per matrix)
  const bf16x8* W0_8 = (const bf16x8*)(Wp);
  const bf16x8* W1_8 = (const bf16x8*)(Wp + 184320);
  const bf16x8* W2_8 = (const bf16x8*)(Wp + 368640);
  const bf16x8 *p0A[3], *p0B[3], *p1A[3], *p1B[3], *p2[3];
  #pragma unroll
  for (int m = 0; m < 3; ++m){
    p0A[m] = W0_8 + (size_t)(m * 15 + jt0a) * (8 * 64)  + lane;
    p0B[m] = W0_8 + (size_t)(m * 15 + jt0b) * (8 * 64)  + lane;
    p1A[m] = W1_8 + (size_t)(m * 10 + jt1a) * (12 * 64) + lane;
    p1B[m] = W1_8 + (size_t)(m * 10 + ((jt1b < 10) ? jt1b : 0)) * (12 * 64) + lane;
    p2[m]  = W2_8 + (size_t)(m * 8  + jt2)  * (9 * 64)  + lane;
  }

  // x_0 into X0 buf0
  if (tid < 16) X0[tid * RS0] = bfbits(xl[tid]);
  __syncthreads();

  // prologue: L0 tile-A weights in flight (loop-carried)
  WG<8> g0[3];
  wload<8>(p0A[0], g0[0]); wload<8>(p0A[1], g0[1]); wload<8>(p0A[2], g0[2]);

  int cur = 0;
  #pragma unroll 1
  for (int t = 0; t < T_; ++t){
    const int nxt = cur ^ 1;
    uint16_t* X0c = X0 + cur * 16 * RS0; uint16_t* X0n = X0 + nxt * 16 * RS0;
    uint16_t* X1c = X1 + cur * 16 * RS1; uint16_t* X1n = X1 + nxt * 16 * RS1;
    uint16_t* X2c = X2 + cur * 16 * RS2; uint16_t* X2n = X2 + nxt * 16 * RS2;

    // ================= layer 0 (KT=8, tiles A,B) =================
    {
      bf16x8 a0[8];
      const uint16_t* arow = X0c + llo * RS0 + lhi * 8;
      #pragma unroll
      for (int k = 0; k < 8; ++k) a0[k] = *(const bf16x8*)(arow + k * 32);

      f32x4 acA0 = {0.f,0.f,0.f,0.f}, acA1 = acA0, acA2 = acA0;
      WG<8> gB[3];
      wmfma<8>(a0, g0[0], acA0); wload<8>(p0B[0], gB[0]);
      wmfma<8>(a0, g0[1], acA1); wload<8>(p0B[1], gB[1]);
      wmfma<8>(a0, g0[2], acA2); wload<8>(p0B[2], gB[2]);
      epilogue<0, 231, 1, RS0, RS1>(acA0, acA1, acA2, jt0a, b0A[0], b0A[1], b0A[2],
                                    X0n, X1c, out, t, b0, llo, lhi);
      f32x4 acB0 = {0.f,0.f,0.f,0.f}, acB1 = acB0, acB2 = acB0;
      WG<6> Ah0, Ah1;
      wmfma<8>(a0, gB[0], acB0); wload<6>(p1A[0], Ah0);          // L1 m0-lo
      wmfma<8>(a0, gB[1], acB1); wload<6>(p1A[0] + 6*64, Ah1);   // L1 m0-hi
      wmfma<8>(a0, gB[2], acB2);
      epilogue<0, 231, 1, RS0, RS1>(acB0, acB1, acB2, jt0b, b0B[0], b0B[1], b0B[2],
                                    X0n, X1c, out, t, b0, llo, lhi);
      BAR();

      // ================= layer 1 (KT=12 as 2x6, tiles A[,B]) =================
      bf16x8 a1[12];
      const uint16_t* brow = X1c + llo * RS1 + lhi * 8;
      #pragma unroll
      for (int k = 0; k < 12; ++k) a1[k] = *(const bf16x8*)(brow + k * 32);

      f32x4 c10 = {0.f,0.f,0.f,0.f}, c11 = c10, c12 = c10;
      WG<6> Ah2, Ah3, Ah4, Ah5;
      WG<9> k0, k1, k2;
      if (wave < 2){
        wmfma<6>(a1,     Ah0, c10); wload<6>(p1A[1],         Ah2);
        wmfma<6>(a1 + 6, Ah1, c10); wload<6>(p1A[1] + 6*64,  Ah3);
        wmfma<6>(a1,     Ah2, c11); wload<6>(p1A[2],         Ah4);
        wmfma<6>(a1 + 6, Ah3, c11); wload<6>(p1A[2] + 6*64,  Ah5);
        WG<6> Bh0, Bh1;
        wmfma<6>(a1,     Ah4, c12); wload<6>(p1B[0],         Bh0);
        wmfma<6>(a1 + 6, Ah5, c12); wload<6>(p1B[0] + 6*64,  Bh1);
        epilogue<1, 153, 231, RS1, RS2>(c10, c11, c12, jt1a, b1A[0], b1A[1], b1A[2],
                                        X1n, X2c, out, t, b0, llo, lhi);
        f32x4 d0 = {0.f,0.f,0.f,0.f}, d1 = d0, d2 = d0;
        WG<6> Bh2, Bh3, Bh4, Bh5;
        wmfma<6>(a1,     Bh0, d0); wload<6>(p1B[1],         Bh2);
        wmfma<6>(a1 + 6, Bh1, d0); wload<6>(p1B[1] + 6*64,  Bh3);
        wmfma<6>(a1,     Bh2, d1); wload<6>(p1B[2],         Bh4);
        wmfma<6>(a1 + 6, Bh3, d1); wload<6>(p1B[2] + 6*64,  Bh5);
        wmfma<6>(a1,     Bh4, d2); wload<9>(p2[0], k0);
        wmfma<6>(a1 + 6, Bh5, d2); wload<9>(p2[1], k1);
        epilogue<1, 153, 231, RS1, RS2>(d0, d1, d2, jt1b, b1B[0], b1B[1], b1B[2],
                                        X1n, X2c, out, t, b0, llo, lhi);
        wload<9>(p2[2], k2);
      } else {
        wmfma<6>(a1,     Ah0, c10); wload<6>(p1A[1],         Ah2);
        wmfma<6>(a1 + 6, Ah1, c10); wload<6>(p1A[1] + 6*64,  Ah3);
        wmfma<6>(a1,     Ah2, c11); wload<6>(p1A[2],         Ah4);
        wmfma<6>(a1 + 6, Ah3, c11); wload<6>(p1A[2] + 6*64,  Ah5);
        wmfma<6>(a1,     Ah4, c12); wload<9>(p2[0], k0);
        wmfma<6>(a1 + 6, Ah5, c12); wload<9>(p2[1], k1);
        epilogue<1, 153, 231, RS1, RS2>(c10, c11, c12, jt1a, b1A[0], b1A[1], b1A[2],
                                        X1n, X2c, out, t, b0, llo, lhi);
        wload<9>(p2[2], k2);
      }
      BAR();

      // ================= layer 2 (KT=9) =================
      bf16x8 a2[9];
      const uint16_t* crow = X2c + llo * RS2 + lhi * 8;
      #pragma unroll
      for (int k = 0; k < 9; ++k) a2[k] = *(const bf16x8*)(crow + k * 32);

      f32x4 e0 = {0.f,0.f,0.f,0.f}, e1 = e0, e2 = e0;
      wmfma<9>(a2, k0, e0); wload<8>(p0A[0], g0[0]);   // prefetch t+1 L0-A
      wmfma<9>(a2, k1, e1); wload<8>(p0A[1], g0[1]);
      wmfma<9>(a2, k2, e2); wload<8>(p0A[2], g0[2]);
      epilogue<2, 128, 153, RS2, RS2>(e0, e1, e2, jt2, b2r[0], b2r[1], b2r[2],
                                      X2n, nullptr, out, t, b0, llo, lhi);
    }

    // x_{t+1} into next buffer's input column
    if (tid < 16 && t + 1 < T_)
      X0n[tid * RS0] = bfbits(xl[(t + 1) * 16 + tid]);
    BAR();
    cur = nxt;
  }

  // rnn_hidden = concat(h0,h1,h2); after 512 steps cur==0
  const size_t OH = (size_t)B_ * T_ * 128;
  for (int i = tid; i < 16 * 512; i += 512){
    int row = i >> 9, c = i & 511;
    float v;
    if (c < 231)      v = bf2f(X0[row * RS0 + 1 + c]);
    else if (c < 384) v = bf2f(X1[row * RS1 + c]);
    else              v = bf2f(X2[row * RS2 + (c - 231)]);
    out[OH + (size_t)(b0 + row) * 512 + c] = v;
  }
}

extern "C" void kernel_launch(void* const* d_in, const int* in_sizes, int n_in,
                              void* d_out, int out_size, void* d_ws, size_t ws_size,
                              hipStream_t stream)
{
  const float* elapsed = (const float*)d_in[0];
  const float* enc     = (const float*)d_in[1];
  const float* W1_0 = (const float*)d_in[2];  const float* b1_0 = (const float*)d_in[3];
  const float* W2_0 = (const float*)d_in[4];  const float* b2_0 = (const float*)d_in[5];
  const float* Wa0  = (const float*)d_in[6];  const float* ba0  = (const float*)d_in[7];
  const float* Wb0  = (const float*)d_in[8];  const float* bb0  = (const float*)d_in[9];
  const float* M0   = (const float*)d_in[10];
  const float* W1_1 = (const float*)d_in[11]; const float* b1_1 = (const float*)d_in[12];
  const float* W2_1 = (const float*)d_in[13]; const float* b2_1 = (const float*)d_in[14];
  const float* Wa1  = (const float*)d_in[15]; const float* ba1  = (const float*)d_in[16];
  const float* Wb1  = (const float*)d_in[17]; const float* bb1  = (const float*)d_in[18];
  const float* M1   = (const float*)d_in[19];
  const float* W1_2 = (const float*)d_in[20]; const float* b1_2 = (const float*)d_in[21];
  const float* W2_2 = (const float*)d_in[22]; const float* b2_2 = (const float*)d_in[23];
  const float* Wa2  = (const float*)d_in[24]; const float* ba2  = (const float*)d_in[25];
  const float* Wb2  = (const float*)d_in[26]; const float* bb2  = (const float*)d_in[27];
  const float* M2   = (const float*)d_in[28];

  uint16_t* wp = (uint16_t*)d_ws;

  pack_w<<<90, 256, 0, stream>>>(W1_0, W2_0, Wa0, Wb0, M0, wp,          15,  8, 231, 232);
  pack_w<<<90, 256, 0, stream>>>(W1_1, W2_1, Wa1, Wb1, M1, wp + 184320, 10, 12, 153, 384);
  pack_w<<<54, 256, 0, stream>>>(W1_2, W2_2, Wa2, Wb2, M2, wp + 368640,  8,  9, 128, 281);

  cfc_main<<<32, 512, 0, stream>>>(elapsed, enc,
                                   b1_0, b2_0, ba0, bb0,
                                   b1_1, b2_1, ba1, bb1,
                                   b1_2, b2_2, ba2, bb2,
                                   wp, (float*)d_out);
}